// Round 1
// baseline (234.573 us; speedup 1.0000x reference)
//
#include <hip/hip_runtime.h>
#include <math.h>

// LIF recurrence: v = v + (x_t - v)/tau; s = sigmoid(v - th); v *= (1 - s)
// x: [B=32, T=512, D=2048] fp32, out: spikes s, same shape.
// One thread per (b, d) chain; sequential over T (nonlinear recurrence, no scan
// decomposition). Coalesced: lanes = consecutive d. Unroll-16 batched prefetch
// to hide HBM latency at 4 waves/CU (B*D/256 = 256 blocks exactly covers 256 CUs).

#define TAU_INV 0.5f
#define TH 1.0f

constexpr int BATCH = 32;
constexpr int TT = 512;
constexpr int DD = 2048;

__global__ __launch_bounds__(256) void lif_kernel(const float* __restrict__ x,
                                                  float* __restrict__ out) {
    int tid = blockIdx.x * blockDim.x + threadIdx.x;  // [0, B*D)
    if (tid >= BATCH * DD) return;
    int b = tid >> 11;        // tid / D
    int d = tid & (DD - 1);   // tid % D
    const float* xp = x + (size_t)b * TT * DD + d;
    float* op = out + (size_t)b * TT * DD + d;

    float v = 0.0f;
    constexpr int U = 16;
    for (int t0 = 0; t0 < TT; t0 += U) {
        float xs[U];
        // 16 independent loads issued back-to-back: keeps ~4 KiB/wave in flight
        #pragma unroll
        for (int i = 0; i < U; ++i) {
            xs[i] = xp[(size_t)(t0 + i) * DD];
        }
        #pragma unroll
        for (int i = 0; i < U; ++i) {
            v = v + (xs[i] - v) * TAU_INV;              // leak/integrate
            float s = 1.0f / (1.0f + __expf(TH - v));   // sigmoid(v - th)
            op[(size_t)(t0 + i) * DD] = s;
            v = v * (1.0f - s);                          // soft reset
        }
    }
}

extern "C" void kernel_launch(void* const* d_in, const int* in_sizes, int n_in,
                              void* d_out, int out_size, void* d_ws, size_t ws_size,
                              hipStream_t stream) {
    const float* x = (const float*)d_in[0];
    float* out = (float*)d_out;
    const int threads = 256;
    const int total = BATCH * DD;                 // 65536 chains
    const int blocks = (total + threads - 1) / threads;  // 256
    lif_kernel<<<blocks, threads, 0, stream>>>(x, out);
}

// Round 2
// 226.808 us; speedup vs baseline: 1.0342x; 1.0342x over previous
//
#include <hip/hip_runtime.h>
#include <math.h>

// LIF recurrence: v = v + (x_t - v)/tau; s = sigmoid(v - th); v *= (1 - s)
// x: [B=32, T=512, D=2048] fp32 -> spikes s, same shape.
// One thread per (b,d) chain, sequential over T (nonlinear recurrence).
// 65536 chains = 1024 waves = 1 wave/SIMD: zero TLP, so latency hiding is
// pure ILP. R1 showed the load->drain->compute phase structure leaves the
// memory pipe idle ~70% of the time (2.5 TB/s observed vs 6.6 achievable).
// Fix: double-buffered software pipeline — prefetch block k+1's 16 loads
// BEFORE computing block k, so ~16 loads (4 KiB/wave) stay in flight
// continuously. Register cost (2x16 floats) is free at 1 wave/SIMD.

#define TAU_INV 0.5f
#define TH 1.0f

constexpr int BATCH = 32;
constexpr int TT = 512;
constexpr int DD = 2048;
constexpr int U = 16;            // time steps per pipeline stage
constexpr int NB = TT / U;       // 32 stages

__global__ __launch_bounds__(256) void lif_kernel(const float* __restrict__ x,
                                                  float* __restrict__ out) {
    int tid = blockIdx.x * blockDim.x + threadIdx.x;  // [0, B*D)
    int b = tid >> 11;        // tid / D
    int d = tid & (DD - 1);   // tid % D
    const float* xp = x + (size_t)b * TT * DD + d;
    float* op = out + (size_t)b * TT * DD + d;

    float buf[2][U];

    // Prologue: fill buffer 0 with stage 0 (t = 0..U-1).
    #pragma unroll
    for (int i = 0; i < U; ++i)
        buf[0][i] = __builtin_nontemporal_load(xp + (size_t)i * DD);

    float v = 0.0f;
    #pragma unroll 2   // makes (blk & 1) compile-time so buf[] stays in regs
    for (int blk = 0; blk < NB; ++blk) {
        const int cur = blk & 1;
        const int nxt = cur ^ 1;

        // Prefetch stage blk+1 BEFORE computing stage blk: the compute
        // below only needs vmcnt to cover buf[cur], so these 16 loads
        // remain in flight under the whole dependent-chain compute.
        if (blk + 1 < NB) {
            const float* xn = xp + (size_t)(blk + 1) * U * DD;
            #pragma unroll
            for (int i = 0; i < U; ++i)
                buf[nxt][i] = __builtin_nontemporal_load(xn + (size_t)i * DD);
        }

        // Compute stage blk (16 dependent LIF steps) + streamed stores.
        float* ob = op + (size_t)blk * U * DD;
        #pragma unroll
        for (int i = 0; i < U; ++i) {
            v = v + (buf[cur][i] - v) * TAU_INV;         // leak/integrate
            float s = 1.0f / (1.0f + __expf(TH - v));    // sigmoid(v - th)
            __builtin_nontemporal_store(s, ob + (size_t)i * DD);
            v = v * (1.0f - s);                           // soft reset
        }
    }
}

extern "C" void kernel_launch(void* const* d_in, const int* in_sizes, int n_in,
                              void* d_out, int out_size, void* d_ws, size_t ws_size,
                              hipStream_t stream) {
    const float* x = (const float*)d_in[0];
    float* out = (float*)d_out;
    const int threads = 256;
    const int total = BATCH * DD;                        // 65536 chains
    const int blocks = (total + threads - 1) / threads;  // 256
    lif_kernel<<<blocks, threads, 0, stream>>>(x, out);
}